// Round 12
// baseline (894.796 us; speedup 1.0000x reference)
//
#include <hip/hip_runtime.h>
#include <hip/hip_bf16.h>

#define DM 512      // d_model
#define DI 1024     // d_inner
#define DSTATE 16
#define DTR 32      // dt_rank
#define NLAYER 8
#define BS 4
#define LL 256      // tokens per batch (F*NP)
#define MT 1024     // BS*LL total tokens
#define DPROJ 256

typedef unsigned short u16;
typedef __attribute__((ext_vector_type(8))) short short8;
typedef __attribute__((ext_vector_type(4))) float f32x4;

__device__ __forceinline__ float sigmoidf_(float x){ return 1.f/(1.f+__expf(-x)); }

// fp32 -> bf16 round-to-nearest-even (finite inputs)
__device__ __forceinline__ u16 f2bf(float f){
  unsigned u = __float_as_uint(f);
  u = (u + 0x7FFF + ((u>>16)&1)) >> 16;
  return (u16)u;
}
__device__ __forceinline__ float bf2f(u16 v){
  return __uint_as_float(((unsigned)v) << 16);
}

// VALU-pipe 16-lane sum via DPP row rotations
template<int CTRL>
__device__ __forceinline__ float dpp_ror_add(float x){
  int y = __builtin_amdgcn_update_dpp(0, __float_as_int(x), CTRL, 0xF, 0xF, false);
  return x + __int_as_float(y);
}
__device__ __forceinline__ float sum16_dpp(float x){
  x = dpp_ror_add<0x128>(x);
  x = dpp_ror_add<0x124>(x);
  x = dpp_ror_add<0x122>(x);
  x = dpp_ror_add<0x121>(x);
  return x;
}

// ---------------- patch embed
__global__ __launch_bounds__(256) void embed_k(const float* __restrict__ ts,
    const float* __restrict__ ew, const float* __restrict__ eb, float* __restrict__ x){
  int idx = blockIdx.x*256 + threadIdx.x;     // MT*DM
  int m = idx >> 9, d = idx & 511;
  int b = m >> 8, np_ = m & 255;
  const float* t0 = ts + b*1024 + np_*4;
  float acc = eb[d];
  #pragma unroll
  for (int p=0;p<4;p++) acc = fmaf(t0[p], ew[d*4+p], acc);
  x[idx] = acc;
}

// ---------------- cast ALL weights to bf16 once; coalesced float4->ushort4
__global__ __launch_bounds__(256) void wcastall_k(
    const float* __restrict__ w_in, const float* __restrict__ w_out,
    const float* __restrict__ w_xp, const float* __restrict__ w_pj,
    u16* __restrict__ dst){
  int t = blockIdx.x*256 + threadIdx.x;   // 6684672 float4s
  long e4 = (long)t*4;
  const float* src; long o;
  if      (e4 < 16777216) { src = w_in;  o = e4; }
  else if (e4 < 25165824) { src = w_out; o = e4 - 16777216; }
  else if (e4 < 26214400) { src = w_xp;  o = e4 - 25165824; }
  else                    { src = w_pj;  o = e4 - 26214400; }
  float4 v = *(const float4*)(src + o);
  ushort4 r; r.x=f2bf(v.x); r.y=f2bf(v.y); r.z=f2bf(v.z); r.w=f2bf(v.w);
  *(ushort4*)(dst + e4) = r;
}

// ---------------- fused (residual combine) + rmsnorm -> bf16 normal+flipped
__global__ __launch_bounds__(256) void rmscomb_k(float* __restrict__ x,
    const float* __restrict__ yout,   // nullptr for layer 0
    const float* __restrict__ nw, u16* __restrict__ xnbf, u16* __restrict__ xnfbf){
  int m = blockIdx.x, t = threadIdx.x;
  int b = m>>8, l = m&255, mf = (b<<8)+(255-l);
  float2 v = *(const float2*)&x[(long)m*DM + t*2];
  if (yout){
    float2 f = *(const float2*)&yout[(long)m*DM + t*2];
    float2 g = *(const float2*)&yout[(long)MT*DM + (long)mf*DM + t*2];
    v.x += f.x + g.x; v.y += f.y + g.y;
    *(float2*)&x[(long)m*DM + t*2] = v;
  }
  float ss = v.x*v.x + v.y*v.y;
  ss += __shfl_down(ss,32); ss += __shfl_down(ss,16); ss += __shfl_down(ss,8);
  ss += __shfl_down(ss,4);  ss += __shfl_down(ss,2);  ss += __shfl_down(ss,1);
  __shared__ float ps[4];
  if ((t&63)==0) ps[t>>6] = ss;
  __syncthreads();
  float tot = ps[0]+ps[1]+ps[2]+ps[3];
  float rs = rsqrtf(tot*(1.f/DM) + 1e-5f);
  ushort2 o; o.x = f2bf(v.x*rs*nw[t*2]); o.y = f2bf(v.y*rs*nw[t*2+1]);
  *(ushort2*)&xnbf [(long)m *DM + t*2] = o;
  *(ushort2*)&xnfbf[(long)mf*DM + t*2] = o;
}

// ---------------- final combine + cast to bf16
__global__ __launch_bounds__(256) void combcast_k(const float* __restrict__ x,
    const float* __restrict__ yout, u16* __restrict__ xbf){
  int idx = blockIdx.x*256 + threadIdx.x;   // MT*DM/4
  int m = idx >> 7, c4 = idx & 127;
  int b = m>>8, l = m&255, mf = (b<<8)+(255-l);
  float4 r = ((const float4*)x)[idx];
  float4 f = ((const float4*)yout)[idx];
  float4 g = ((const float4*)(yout + (long)MT*DM))[(long)mf*128 + c4];
  ushort4 o;
  o.x = f2bf(r.x + f.x + g.x); o.y = f2bf(r.y + f.y + g.y);
  o.z = f2bf(r.z + f.z + g.z); o.w = f2bf(r.w + f.w + g.w);
  ((ushort4*)xbf)[idx] = o;
}

// ---------------- bf16 MFMA GEMM: C = A @ W^T
// SPLITK>1: z = dir*SPLITK+kc, fp32 partials at C + z*M*N.
// EPI: 0 plain | 2 final scatter+bias | 4 in_proj split: n<1024 -> fp32 C, n>=1024 -> bf16 silu -> G
template<int BM,int BN,int SPLITK,int EPI>
__global__ __launch_bounds__(256) void mfma_nt(
    const u16* __restrict__ A, int lda, long sA,
    const u16* __restrict__ W, int ldw, long sW,
    const float* __restrict__ bias, u16* __restrict__ G,
    float* __restrict__ C, int ldc, long sC,
    int M, int N, int K)
{
  constexpr int WM = BM/2, WN = BN/2;
  constexpr int MI = WM/16, NI = WN/16;
  int z = blockIdx.z;
  int dir = z / SPLITK, kc = z % SPLITK;
  int Klen = K / SPLITK;
  int kbase = kc * Klen;
  A += (long)dir * sA;
  W += (long)dir * sW;
  if (SPLITK > 1) C += (long)z * M * N; else C += (long)dir * sC;
  if (EPI==4) G += (long)dir * (long)MT*DI;

  __shared__ u16 Al[BM*32];
  __shared__ u16 Wl[BN*32];
  int tid = threadIdx.x;
  int lane = tid & 63;
  int wave = tid >> 6;
  int wm0 = (wave>>1)*WM, wn0 = (wave&1)*WN;
  int m0 = blockIdx.y*BM, n0 = blockIdx.x*BN;
  int l16 = lane>>4, l15 = lane&15;

  f32x4 acc[MI][NI] = {};

  for (int k0=0; k0<Klen; k0+=32){
    #pragma unroll
    for (int it=0; it<BM*4/256; ++it){
      int ch = it*256 + tid;
      int row = ch % BM, kk = ch / BM;
      const u16* g = A + (long)(m0+row)*lda + kbase + k0 + kk*8;
      __builtin_amdgcn_global_load_lds(
          (const __attribute__((address_space(1))) void*)g,
          (__attribute__((address_space(3))) void*)(Al + ch*8), 16, 0, 0);
    }
    #pragma unroll
    for (int it=0; it<BN*4/256; ++it){
      int ch = it*256 + tid;
      int row = ch % BN, kk = ch / BN;
      const u16* g = W + (long)(n0+row)*ldw + kbase + k0 + kk*8;
      __builtin_amdgcn_global_load_lds(
          (const __attribute__((address_space(1))) void*)g,
          (__attribute__((address_space(3))) void*)(Wl + ch*8), 16, 0, 0);
    }
    __syncthreads();
    short8 a[MI], b[NI];
    #pragma unroll
    for (int i=0;i<MI;i++)
      a[i] = *(const short8*)&Al[(l16*BM + wm0 + i*16 + l15)*8];
    #pragma unroll
    for (int j=0;j<NI;j++)
      b[j] = *(const short8*)&Wl[(l16*BN + wn0 + j*16 + l15)*8];
    #pragma unroll
    for (int i=0;i<MI;i++)
      #pragma unroll
      for (int j=0;j<NI;j++)
        acc[i][j] = __builtin_amdgcn_mfma_f32_16x16x32_bf16(a[i], b[j], acc[i][j], 0,0,0);
    __syncthreads();
  }
  #pragma unroll
  for (int i=0;i<MI;i++){
    #pragma unroll
    for (int j=0;j<NI;j++){
      #pragma unroll
      for (int r=0;r<4;r++){
        int m = m0 + wm0 + i*16 + l16*4 + r;
        int n = n0 + wn0 + j*16 + l15;
        float v = acc[i][j][r];
        if (EPI==2){
          v += bias[n];
          int bb = m>>8, np_ = m&255, p = n>>8, dp = n&255;
          C[((long)(bb*1024 + np_*4 + p))*256 + dp] = v;
        } else if (EPI==4){
          if (n < 1024) C[(long)m*1024 + n] = v;
          else          G[(long)m*1024 + (n-1024)] = f2bf(v * sigmoidf_(v));
        } else {
          C[(long)m*ldc + n] = v;
        }
      }
    }
  }
}

// ---------------- split-K reduce for xproj
__global__ __launch_bounds__(256) void xreduce_k(const float* __restrict__ part,
    float* __restrict__ xdbl){
  int idx = blockIdx.x*256 + threadIdx.x;   // 131072
  int d = idx >> 16, off = idx & 65535;
  float s = 0.f;
  #pragma unroll
  for (int kc=0; kc<8; ++kc) s += part[((d*8+kc)<<16) + off];
  xdbl[idx] = s;
}

// ---------------- causal depthwise conv + bias + silu -> bf16 u (reads dense xz_u)
__global__ __launch_bounds__(256) void conv_silu_k(const float* __restrict__ xzu,
    const float* __restrict__ cw, const float* __restrict__ cb,
    u16* __restrict__ ubf){
  int idx = blockIdx.x*256 + threadIdx.x;   // 2*MT*DI/4 = 524288
  int e = idx & (DI-1);
  int grp = idx >> 10;          // 512 groups: dir(1) | b(2) | lg(6)
  int dir = grp >> 8;
  int b   = (grp >> 6) & 3;
  int l0  = (grp & 63) * 4;
  long dm0 = (long)dir*MT + b*LL + l0;
  const float* w = cw + ((long)dir*DI + e)*4;
  float w0=w[0], w1=w[1], w2=w[2], w3=w[3];
  float bias = cb[dir*DI + e];
  const float* src = xzu + dm0*DI + e;     // row l0
  float vb[7];
  #pragma unroll
  for (int j=0;j<7;j++){
    int l = l0 - 3 + j;
    vb[j] = (l >= 0) ? src[(long)(j-3)*DI] : 0.f;
  }
  #pragma unroll
  for (int j=0;j<4;j++){
    float acc = bias;
    acc = fmaf(w0, vb[j],   acc);
    acc = fmaf(w1, vb[j+1], acc);
    acc = fmaf(w2, vb[j+2], acc);
    acc = fmaf(w3, vb[j+3], acc);
    float v = acc * sigmoidf_(acc);
    ubf[(dm0+j)*DI + e] = f2bf(v);
  }
}

// ---------------- selective scan: 1024 threads, 4 L-groups x 64, 2-phase prefix scan
// thread = (lg 0..3, el 0..15, n 0..15); grid (64, B, 2) XCD-remapped
__global__ __launch_bounds__(1024) void scan_k(
    const u16* __restrict__ ubf, const u16* __restrict__ gbf,
    const float* __restrict__ xdbl, const float* __restrict__ dtw,
    const float* __restrict__ dtb, const float* __restrict__ A_log,
    const float* __restrict__ Dp, u16* __restrict__ ygbf)
{
  int t = threadIdx.x;
  int n  = t & 15;
  int el = (t >> 4) & 15;
  int lg = t >> 8;                 // 0..3
  int id = blockIdx.x + 64*blockIdx.y + 256*blockIdx.z;   // 0..511
  int xcd = id & 7, slot = id >> 3;
  int ec = xcd*8 + (slot & 7);
  int bd = slot >> 3;
  int b = bd & 3, dir = bd >> 2;
  int e0 = ec*16;

  long mbase = (long)dir*MT + b*LL;
  const u16* up_ = ubf + mbase*DI;
  const u16* gp_ = gbf + mbase*DI;
  const float* xd_ = xdbl + mbase*64;
  u16* yp_ = ygbf + mbase*DI;

  // walk-role constants (state (e0+el, n))
  float Av = -__expf(A_log[((long)dir*DI + e0 + el)*16 + n]);
  float Dv = Dp[dir*DI + e0 + el];

  __shared__ float sDU[16][516];     // [e_local][l*2 + {0:d,1:u}]
  __shared__ float sBC[16][516];     // [n][l*2 + {0:B,1:C}]
  __shared__ float sy [256][20];
  __shared__ float sH [4][16][16];
  __shared__ float sA [4][16][16];
  __shared__ float sHin[4][16][16];

  // ---- stage u (1024 ushort4) and issue g load (consumed at end)
  int sl = t >> 2, se4 = (t & 3) * 4;
  ushort4 gv = *(const ushort4*)&gp_[(long)sl*DI + e0 + se4];
  {
    ushort4 uv = *(const ushort4*)&up_[(long)sl*DI + e0 + se4];
    sDU[se4  ][sl*2+1] = bf2f(uv.x);
    sDU[se4+1][sl*2+1] = bf2f(uv.y);
    sDU[se4+2][sl*2+1] = bf2f(uv.z);
    sDU[se4+3][sl*2+1] = bf2f(uv.w);
  }
  // ---- stage B/C (2048 float4, 2 per thread)
  #pragma unroll
  for (int h_=0; h_<2; ++h_){
    int f = t + h_*1024;
    int row = f >> 3, c4 = (f & 7) * 4;      // source col = 32 + c4
    float4 v = *(const float4*)&xd_[(long)row*64 + 32 + c4];
    if (c4 < 16){
      int nb = c4;
      sBC[nb  ][row*2] = v.x; sBC[nb+1][row*2] = v.y;
      sBC[nb+2][row*2] = v.z; sBC[nb+3][row*2] = v.w;
    } else {
      int nb = c4 - 16;
      sBC[nb  ][row*2+1] = v.x; sBC[nb+1][row*2+1] = v.y;
      sBC[nb+2][row*2+1] = v.z; sBC[nb+3][row*2+1] = v.w;
    }
  }
  // ---- delta: thread computes delta(l = lg*64 + el*4 + j, e = e0+n)
  {
    float wrow[32];
    const float* wr = dtw + ((long)dir*DI + e0 + n)*32;
    #pragma unroll
    for (int r4=0;r4<8;r4++) *(float4*)&wrow[r4*4] = *(const float4*)&wr[r4*4];
    float dtbv = dtb[dir*DI + e0 + n];
    #pragma unroll
    for (int j=0;j<4;j++){
      int l = lg*64 + el*4 + j;
      const float* row = &xd_[(long)l*64];
      float acc = dtbv;
      #pragma unroll
      for (int r4=0;r4<8;r4++){
        float4 d4 = *(const float4*)&row[r4*4];
        acc = fmaf(d4.x, wrow[r4*4],   acc);
        acc = fmaf(d4.y, wrow[r4*4+1], acc);
        acc = fmaf(d4.z, wrow[r4*4+2], acc);
        acc = fmaf(d4.w, wrow[r4*4+3], acc);
      }
      acc = fmaxf(acc, 0.f) + __logf(1.f + __expf(-fabsf(acc)));
      sDU[n][l*2] = acc;
    }
  }
  __syncthreads();

  // ---- phase 1: local scan (h_in = 0), track running product
  const float* pDU = &sDU[el][lg*128];
  const float* pBC = &sBC[n][lg*128];
  int lbase = lg*64;
  float h = 0.f, ap = 1.f;
  #pragma unroll 8
  for (int l2 = 0; l2 < 32; ++l2){
    float4 du = *(const float4*)&pDU[l2*4];
    float4 bc = *(const float4*)&pBC[l2*4];
    {
      float dA = __expf(du.x*Av);
      h = fmaf(dA, h, du.x*du.y*bc.x);
      ap *= dA;
      float yc = sum16_dpp(h*bc.y);
      if (n==0) sy[lbase+2*l2][el] = yc + du.y*Dv;
    }
    {
      float dA = __expf(du.z*Av);
      h = fmaf(dA, h, du.z*du.w*bc.z);
      ap *= dA;
      float yc = sum16_dpp(h*bc.w);
      if (n==0) sy[lbase+2*l2+1][el] = yc + du.w*Dv;
    }
  }
  sH[lg][el][n] = h;
  sA[lg][el][n] = ap;
  __syncthreads();

  // ---- phase 2: prefix combine of group summaries (threads t<256)
  if (t < 256){
    float hin = 0.f;
    sHin[0][el][n] = 0.f;
    #pragma unroll
    for (int g=1; g<4; ++g){
      hin = sH[g-1][el][n] + sA[g-1][el][n]*hin;
      sHin[g][el][n] = hin;
    }
  }
  __syncthreads();

  // ---- phase 3: correction walk for groups 1..3
  if (lg > 0){
    float hin = sHin[lg][el][n];
    float p = 1.f;
    #pragma unroll 8
    for (int l2 = 0; l2 < 32; ++l2){
      float4 du = *(const float4*)&pDU[l2*4];
      float4 bc = *(const float4*)&pBC[l2*4];
      {
        p *= __expf(du.x*Av);
        float yc = sum16_dpp(p*hin*bc.y);
        if (n==0) sy[lbase+2*l2][el] += yc;
      }
      {
        p *= __expf(du.z*Av);
        float yc = sum16_dpp(p*hin*bc.w);
        if (n==0) sy[lbase+2*l2+1][el] += yc;
      }
    }
  }
  __syncthreads();

  // ---- gated bf16 store (1024 ushort4)
  {
    float4 y4 = *(const float4*)&sy[sl][se4];
    ushort4 o;
    o.x = f2bf(y4.x * bf2f(gv.x)); o.y = f2bf(y4.y * bf2f(gv.y));
    o.z = f2bf(y4.z * bf2f(gv.z)); o.w = f2bf(y4.w * bf2f(gv.w));
    *(ushort4*)&yp_[(long)sl*DI + e0 + se4] = o;
  }
}

extern "C" void kernel_launch(void* const* d_in, const int* in_sizes, int n_in,
                              void* d_out, int out_size, void* d_ws, size_t ws_size,
                              hipStream_t stream){
  const float* ts   = (const float*)d_in[0];
  const float* ew   = (const float*)d_in[2];
  const float* eb   = (const float*)d_in[3];
  const float* nw   = (const float*)d_in[4];
  const float* inw  = (const float*)d_in[5];
  const float* cw   = (const float*)d_in[6];
  const float* cb   = (const float*)d_in[7];
  const float* xpw  = (const float*)d_in[8];
  const float* dtw  = (const float*)d_in[9];
  const float* dtb  = (const float*)d_in[10];
  const float* alog = (const float*)d_in[11];
  const float* dpp  = (const float*)d_in[12];
  const float* outw = (const float*)d_in[13];
  const float* pw   = (const float*)d_in[14];
  const float* pb   = (const float*)d_in[15];
  float* out = (float*)d_out;

  float* ws   = (float*)d_ws;
  float* x    = ws;                  // 524288
  float* xzu  = ws + 524288;         // 2097152 (u pre-conv, both dirs)
  float* xdbl = ws + 2621440;        // 131072
  float* yout = ws + 2752512;        // 1048576
  float* xpart= ws + 3801088;        // 1048576 (2*8*65536)
  u16* ub     = (u16*)(ws + 4849664);
  u16* xn_bf  = ub;                  // 1048576 (both dirs)
  u16* u_bf   = ub + 1048576;        // 2097152
  u16* g_bf   = ub + 3145728;        // 2097152 (silu(z), both dirs)
  u16* yg_bf  = ub + 5242880;        // 2097152
  u16* x_bf   = ub + 7340032;        // 524288
  u16* wb     = ub + 7864320;        // 26738688 bf16 weights (in|out|xp|pj)
  u16* wb_in  = wb;                  // 16777216
  u16* wb_out = wb + 16777216;       // 8388608
  u16* wb_xp  = wb + 25165824;       // 1048576
  u16* wb_pj  = wb + 26214400;       // 524288

  dim3 blk(256);

  embed_k<<<MT*DM/256, blk, 0, stream>>>(ts, ew, eb, x);
  wcastall_k<<<26112, blk, 0, stream>>>(inw, outw, xpw, pw, wb);

  for (int i=0;i<NLAYER;i++){
    rmscomb_k<<<MT, blk, 0, stream>>>(x, i ? yout : nullptr, nw + i*DM,
        xn_bf, xn_bf + MT*DM);
    // in_proj: (1024x512)@(2048x512)^T; u-half -> xzu fp32, z-half -> silu bf16 g
    mfma_nt<64,128,1,4><<<dim3(16,16,2), blk, 0, stream>>>(
        xn_bf, DM, (long)MT*DM, wb_in + (long)i*2097152, DM, 1048576,
        nullptr, g_bf, xzu, 1024, (long)MT*1024, MT, 2048, DM);
    conv_silu_k<<<2048, blk, 0, stream>>>(xzu, cw + (long)i*2*DI*4, cb + i*2*DI, u_bf);
    // xproj: (1024x1024)@(64x1024)^T split-K=8, 64x64 tiles, 256 blocks
    mfma_nt<64,64,8,0><<<dim3(1,16,16), blk, 0, stream>>>(
        u_bf, DI, (long)MT*DI, wb_xp + (long)i*131072, DI, 65536,
        nullptr, nullptr, xpart, 64, 0, MT, 64, DI);
    xreduce_k<<<512, blk, 0, stream>>>(xpart, xdbl);
    // scan: 1024-thread group-parallel prefix scan, fused fp32 delta-GEMM
    scan_k<<<dim3(64, BS, 2), dim3(1024), 0, stream>>>(u_bf, g_bf, xdbl,
        dtw + (long)i*2*DI*DTR, dtb + (long)i*2*DI,
        alog + (long)i*2*DI*16, dpp + i*2*DI, yg_bf);
    // out_proj: (1024x1024)@(512x1024)^T; 64x64 tiles, 256 blocks
    mfma_nt<64,64,1,0><<<dim3(8,16,2), blk, 0, stream>>>(
        yg_bf, DI, (long)MT*DI, wb_out + (long)i*1048576, DI, 524288,
        nullptr, nullptr, yout, DM, (long)MT*DM, MT, DM, DI);
  }
  combcast_k<<<MT*DM/4/256, blk, 0, stream>>>(x, yout, x_bf);
  // final proj + bias + scatter; 64x64 tiles, 256 blocks
  mfma_nt<64,64,1,2><<<dim3(16,16,1), blk, 0, stream>>>(
      x_bf, DM, 0, wb_pj, DM, 0, pb, nullptr, out, 1024, 0, MT, 1024, DM);
}

// Round 13
// 876.156 us; speedup vs baseline: 1.0213x; 1.0213x over previous
//
#include <hip/hip_runtime.h>
#include <hip/hip_bf16.h>

#define DM 512      // d_model
#define DI 1024     // d_inner
#define DSTATE 16
#define DTR 32      // dt_rank
#define NLAYER 8
#define BS 4
#define LL 256      // tokens per batch (F*NP)
#define MT 1024     // BS*LL total tokens
#define DPROJ 256

typedef unsigned short u16;
typedef unsigned int u32;
typedef __attribute__((ext_vector_type(8))) short short8;
typedef __attribute__((ext_vector_type(4))) float f32x4;

__device__ __forceinline__ float sigmoidf_(float x){ return 1.f/(1.f+__expf(-x)); }

// fp32 -> bf16 round-to-nearest-even (finite inputs)
__device__ __forceinline__ u16 f2bf(float f){
  unsigned u = __float_as_uint(f);
  u = (u + 0x7FFF + ((u>>16)&1)) >> 16;
  return (u16)u;
}
__device__ __forceinline__ float bf2f(u16 v){
  return __uint_as_float(((unsigned)v) << 16);
}

// VALU-pipe 16-lane sum via DPP row rotations
template<int CTRL>
__device__ __forceinline__ float dpp_ror_add(float x){
  int y = __builtin_amdgcn_update_dpp(0, __float_as_int(x), CTRL, 0xF, 0xF, false);
  return x + __int_as_float(y);
}
__device__ __forceinline__ float sum16_dpp(float x){
  x = dpp_ror_add<0x128>(x);
  x = dpp_ror_add<0x124>(x);
  x = dpp_ror_add<0x122>(x);
  x = dpp_ror_add<0x121>(x);
  return x;
}

// ---------------- patch embed
__global__ __launch_bounds__(256) void embed_k(const float* __restrict__ ts,
    const float* __restrict__ ew, const float* __restrict__ eb, float* __restrict__ x){
  int idx = blockIdx.x*256 + threadIdx.x;     // MT*DM
  int m = idx >> 9, d = idx & 511;
  int b = m >> 8, np_ = m & 255;
  const float* t0 = ts + b*1024 + np_*4;
  float acc = eb[d];
  #pragma unroll
  for (int p=0;p<4;p++) acc = fmaf(t0[p], ew[d*4+p], acc);
  x[idx] = acc;
}

// ---------------- cast ALL weights to bf16 once; coalesced float4->ushort4
__global__ __launch_bounds__(256) void wcastall_k(
    const float* __restrict__ w_in, const float* __restrict__ w_out,
    const float* __restrict__ w_xp, const float* __restrict__ w_pj,
    u16* __restrict__ dst){
  int t = blockIdx.x*256 + threadIdx.x;   // 6684672 float4s
  long e4 = (long)t*4;
  const float* src; long o;
  if      (e4 < 16777216) { src = w_in;  o = e4; }
  else if (e4 < 25165824) { src = w_out; o = e4 - 16777216; }
  else if (e4 < 26214400) { src = w_xp;  o = e4 - 25165824; }
  else                    { src = w_pj;  o = e4 - 26214400; }
  float4 v = *(const float4*)(src + o);
  ushort4 r; r.x=f2bf(v.x); r.y=f2bf(v.y); r.z=f2bf(v.z); r.w=f2bf(v.w);
  *(ushort4*)(dst + e4) = r;
}

// ---------------- fused (residual combine) + rmsnorm -> bf16 normal+flipped
__global__ __launch_bounds__(256) void rmscomb_k(float* __restrict__ x,
    const float* __restrict__ yout,   // nullptr for layer 0
    const float* __restrict__ nw, u16* __restrict__ xnbf, u16* __restrict__ xnfbf){
  int m = blockIdx.x, t = threadIdx.x;
  int b = m>>8, l = m&255, mf = (b<<8)+(255-l);
  float2 v = *(const float2*)&x[(long)m*DM + t*2];
  if (yout){
    float2 f = *(const float2*)&yout[(long)m*DM + t*2];
    float2 g = *(const float2*)&yout[(long)MT*DM + (long)mf*DM + t*2];
    v.x += f.x + g.x; v.y += f.y + g.y;
    *(float2*)&x[(long)m*DM + t*2] = v;
  }
  float ss = v.x*v.x + v.y*v.y;
  ss += __shfl_down(ss,32); ss += __shfl_down(ss,16); ss += __shfl_down(ss,8);
  ss += __shfl_down(ss,4);  ss += __shfl_down(ss,2);  ss += __shfl_down(ss,1);
  __shared__ float ps[4];
  if ((t&63)==0) ps[t>>6] = ss;
  __syncthreads();
  float tot = ps[0]+ps[1]+ps[2]+ps[3];
  float rs = rsqrtf(tot*(1.f/DM) + 1e-5f);
  ushort2 o; o.x = f2bf(v.x*rs*nw[t*2]); o.y = f2bf(v.y*rs*nw[t*2+1]);
  *(ushort2*)&xnbf [(long)m *DM + t*2] = o;
  *(ushort2*)&xnfbf[(long)mf*DM + t*2] = o;
}

// ---------------- final combine + cast to bf16
__global__ __launch_bounds__(256) void combcast_k(const float* __restrict__ x,
    const float* __restrict__ yout, u16* __restrict__ xbf){
  int idx = blockIdx.x*256 + threadIdx.x;   // MT*DM/4
  int m = idx >> 7, c4 = idx & 127;
  int b = m>>8, l = m&255, mf = (b<<8)+(255-l);
  float4 r = ((const float4*)x)[idx];
  float4 f = ((const float4*)yout)[idx];
  float4 g = ((const float4*)(yout + (long)MT*DM))[(long)mf*128 + c4];
  ushort4 o;
  o.x = f2bf(r.x + f.x + g.x); o.y = f2bf(r.y + f.y + g.y);
  o.z = f2bf(r.z + f.z + g.z); o.w = f2bf(r.w + f.w + g.w);
  ((ushort4*)xbf)[idx] = o;
}

// ---------------- bf16 MFMA GEMM: C = A @ W^T
// SPLITK>1: z = dir*SPLITK+kc, fp32 partials at C + z*M*N.
// EPI: 0 plain | 2 final scatter+bias | 4 in_proj split: n<1024 -> fp32 C, n>=1024 -> bf16 silu -> G
template<int BM,int BN,int SPLITK,int EPI>
__global__ __launch_bounds__(256) void mfma_nt(
    const u16* __restrict__ A, int lda, long sA,
    const u16* __restrict__ W, int ldw, long sW,
    const float* __restrict__ bias, u16* __restrict__ G,
    float* __restrict__ C, int ldc, long sC,
    int M, int N, int K)
{
  constexpr int WM = BM/2, WN = BN/2;
  constexpr int MI = WM/16, NI = WN/16;
  int z = blockIdx.z;
  int dir = z / SPLITK, kc = z % SPLITK;
  int Klen = K / SPLITK;
  int kbase = kc * Klen;
  A += (long)dir * sA;
  W += (long)dir * sW;
  if (SPLITK > 1) C += (long)z * M * N; else C += (long)dir * sC;
  if (EPI==4) G += (long)dir * (long)MT*DI;

  __shared__ u16 Al[BM*32];
  __shared__ u16 Wl[BN*32];
  int tid = threadIdx.x;
  int lane = tid & 63;
  int wave = tid >> 6;
  int wm0 = (wave>>1)*WM, wn0 = (wave&1)*WN;
  int m0 = blockIdx.y*BM, n0 = blockIdx.x*BN;
  int l16 = lane>>4, l15 = lane&15;

  f32x4 acc[MI][NI] = {};

  for (int k0=0; k0<Klen; k0+=32){
    #pragma unroll
    for (int it=0; it<BM*4/256; ++it){
      int ch = it*256 + tid;
      int row = ch % BM, kk = ch / BM;
      const u16* g = A + (long)(m0+row)*lda + kbase + k0 + kk*8;
      __builtin_amdgcn_global_load_lds(
          (const __attribute__((address_space(1))) void*)g,
          (__attribute__((address_space(3))) void*)(Al + ch*8), 16, 0, 0);
    }
    #pragma unroll
    for (int it=0; it<BN*4/256; ++it){
      int ch = it*256 + tid;
      int row = ch % BN, kk = ch / BN;
      const u16* g = W + (long)(n0+row)*ldw + kbase + k0 + kk*8;
      __builtin_amdgcn_global_load_lds(
          (const __attribute__((address_space(1))) void*)g,
          (__attribute__((address_space(3))) void*)(Wl + ch*8), 16, 0, 0);
    }
    __syncthreads();
    short8 a[MI], b[NI];
    #pragma unroll
    for (int i=0;i<MI;i++)
      a[i] = *(const short8*)&Al[(l16*BM + wm0 + i*16 + l15)*8];
    #pragma unroll
    for (int j=0;j<NI;j++)
      b[j] = *(const short8*)&Wl[(l16*BN + wn0 + j*16 + l15)*8];
    #pragma unroll
    for (int i=0;i<MI;i++)
      #pragma unroll
      for (int j=0;j<NI;j++)
        acc[i][j] = __builtin_amdgcn_mfma_f32_16x16x32_bf16(a[i], b[j], acc[i][j], 0,0,0);
    __syncthreads();
  }
  #pragma unroll
  for (int i=0;i<MI;i++){
    #pragma unroll
    for (int j=0;j<NI;j++){
      #pragma unroll
      for (int r=0;r<4;r++){
        int m = m0 + wm0 + i*16 + l16*4 + r;
        int n = n0 + wn0 + j*16 + l15;
        float v = acc[i][j][r];
        if (EPI==2){
          v += bias[n];
          int bb = m>>8, np_ = m&255, p = n>>8, dp = n&255;
          C[((long)(bb*1024 + np_*4 + p))*256 + dp] = v;
        } else if (EPI==4){
          if (n < 1024) C[(long)m*1024 + n] = v;
          else          G[(long)m*1024 + (n-1024)] = f2bf(v * sigmoidf_(v));
        } else {
          C[(long)m*ldc + n] = v;
        }
      }
    }
  }
}

// ---------------- split-K reduce for xproj
__global__ __launch_bounds__(256) void xreduce_k(const float* __restrict__ part,
    float* __restrict__ xdbl){
  int idx = blockIdx.x*256 + threadIdx.x;   // 131072
  int d = idx >> 16, off = idx & 65535;
  float s = 0.f;
  #pragma unroll
  for (int kc=0; kc<8; ++kc) s += part[((d*8+kc)<<16) + off];
  xdbl[idx] = s;
}

// ---------------- causal depthwise conv + bias + silu -> bf16 u (reads dense xz_u)
__global__ __launch_bounds__(256) void conv_silu_k(const float* __restrict__ xzu,
    const float* __restrict__ cw, const float* __restrict__ cb,
    u16* __restrict__ ubf){
  int idx = blockIdx.x*256 + threadIdx.x;   // 2*MT*DI/4 = 524288
  int e = idx & (DI-1);
  int grp = idx >> 10;          // 512 groups: dir(1) | b(2) | lg(6)
  int dir = grp >> 8;
  int b   = (grp >> 6) & 3;
  int l0  = (grp & 63) * 4;
  long dm0 = (long)dir*MT + b*LL + l0;
  const float* w = cw + ((long)dir*DI + e)*4;
  float w0=w[0], w1=w[1], w2=w[2], w3=w[3];
  float bias = cb[dir*DI + e];
  const float* src = xzu + dm0*DI + e;     // row l0
  float vb[7];
  #pragma unroll
  for (int j=0;j<7;j++){
    int l = l0 - 3 + j;
    vb[j] = (l >= 0) ? src[(long)(j-3)*DI] : 0.f;
  }
  #pragma unroll
  for (int j=0;j<4;j++){
    float acc = bias;
    acc = fmaf(w0, vb[j],   acc);
    acc = fmaf(w1, vb[j+1], acc);
    acc = fmaf(w2, vb[j+2], acc);
    acc = fmaf(w3, vb[j+3], acc);
    float v = acc * sigmoidf_(acc);
    ubf[(dm0+j)*DI + e] = f2bf(v);
  }
}

// ---------------- selective scan: 1024 threads, 4 L-groups x 64, prefix scan
// bf16 u / packed-bf16 BC in LDS (74KB -> 2 blocks/CU = 32 waves/CU)
// thread = (lg 0..3, el 0..15, n 0..15); grid (64, B, 2) XCD-remapped
__global__ __launch_bounds__(1024) void scan_k(
    const u16* __restrict__ ubf, const u16* __restrict__ gbf,
    const float* __restrict__ xdbl, const float* __restrict__ dtw,
    const float* __restrict__ dtb, const float* __restrict__ A_log,
    const float* __restrict__ Dp, u16* __restrict__ ygbf)
{
  int t = threadIdx.x;
  int n  = t & 15;
  int el = (t >> 4) & 15;
  int lg = t >> 8;                 // 0..3
  int id = blockIdx.x + 64*blockIdx.y + 256*blockIdx.z;   // 0..511
  int xcd = id & 7, slot = id >> 3;
  int ec = xcd*8 + (slot & 7);
  int bd = slot >> 3;
  int b = bd & 3, dir = bd >> 2;
  int e0 = ec*16;

  long mbase = (long)dir*MT + b*LL;
  const u16* up_ = ubf + mbase*DI;
  const u16* gp_ = gbf + mbase*DI;
  const float* xd_ = xdbl + mbase*64;
  u16* yp_ = ygbf + mbase*DI;

  float Av = -__expf(A_log[((long)dir*DI + e0 + el)*16 + n]);
  float Dv = Dp[dir*DI + e0 + el];

  __shared__ float sD [16][260];     // [e_local][l] fp32 delta
  __shared__ u16   sU [16][260];     // [e_local][l] bf16 u
  __shared__ u32   sBC[16][260];     // [n][l] packed lo=B, hi=C (bf16)
  __shared__ float sy [256][20];
  __shared__ float sH [4][16][16];
  __shared__ float sA [4][16][16];
  __shared__ float sHin[4][16][16];

  // ---- stage u (1024 ushort4) + issue g load (epilogue)
  int sl = t >> 2, se4 = (t & 3) * 4;          // sl 0..255, se4 0/4/8/12
  ushort4 gv = *(const ushort4*)&gp_[(long)sl*DI + e0 + se4];
  {
    ushort4 uv = *(const ushort4*)&up_[(long)sl*DI + e0 + se4];
    sU[se4  ][sl] = uv.x; sU[se4+1][sl] = uv.y;
    sU[se4+2][sl] = uv.z; sU[se4+3][sl] = uv.w;
  }
  // ---- stage B,C packed (per thread: one row-quad of B and of C)
  {
    float4 B4 = *(const float4*)&xd_[(long)sl*64 + 32 + se4];
    float4 C4 = *(const float4*)&xd_[(long)sl*64 + 48 + se4];
    sBC[se4  ][sl] = (u32)f2bf(B4.x) | ((u32)f2bf(C4.x) << 16);
    sBC[se4+1][sl] = (u32)f2bf(B4.y) | ((u32)f2bf(C4.y) << 16);
    sBC[se4+2][sl] = (u32)f2bf(B4.z) | ((u32)f2bf(C4.z) << 16);
    sBC[se4+3][sl] = (u32)f2bf(B4.w) | ((u32)f2bf(C4.w) << 16);
  }
  // ---- delta: thread (n, lq = t>>4 0..63) computes 4 l's at e-col n
  {
    float wrow[32];
    const float* wr = dtw + ((long)dir*DI + e0 + n)*32;
    #pragma unroll
    for (int r4=0;r4<8;r4++) *(float4*)&wrow[r4*4] = *(const float4*)&wr[r4*4];
    float dtbv = dtb[dir*DI + e0 + n];
    int lq = t >> 4;                            // 0..63
    #pragma unroll
    for (int j=0;j<4;j++){
      int l = lq*4 + j;
      const float* row = &xd_[(long)l*64];
      float acc = dtbv;
      #pragma unroll
      for (int r4=0;r4<8;r4++){
        float4 d4 = *(const float4*)&row[r4*4];
        acc = fmaf(d4.x, wrow[r4*4],   acc);
        acc = fmaf(d4.y, wrow[r4*4+1], acc);
        acc = fmaf(d4.z, wrow[r4*4+2], acc);
        acc = fmaf(d4.w, wrow[r4*4+3], acc);
      }
      acc = fmaxf(acc, 0.f) + __logf(1.f + __expf(-fabsf(acc)));
      sD[n][l] = acc;
    }
  }
  __syncthreads();

  // ---- phase 1: local scan (h_in = 0), track running product ap
  const float* pD  = &sD[el][lg*64];
  const u16*   pU  = &sU[el][lg*64];
  const u32*   pBC = &sBC[n][lg*64];
  int lbase = lg*64;
  float h = 0.f, ap = 1.f;
  #pragma unroll 4
  for (int l4 = 0; l4 < 16; ++l4){
    f32x4 d4 = *(const f32x4*)&pD[l4*4];
    ushort4 u4 = *(const ushort4*)&pU[l4*4];
    uint4 bc4 = *(const uint4*)&pBC[l4*4];
    float uvk[4] = { bf2f(u4.x), bf2f(u4.y), bf2f(u4.z), bf2f(u4.w) };
    u32 bck[4] = { bc4.x, bc4.y, bc4.z, bc4.w };
    #pragma unroll
    for (int k=0;k<4;k++){
      float dv = d4[k];
      float uv = uvk[k];
      float Bv = bf2f((u16)(bck[k] & 0xffff));
      float Cv = bf2f((u16)(bck[k] >> 16));
      float dA = __expf(dv*Av);
      h = fmaf(dA, h, dv*uv*Bv);
      ap *= dA;
      float yc = sum16_dpp(h*Cv);
      if (n==0) sy[lbase + l4*4 + k][el] = yc + uv*Dv;
    }
  }
  sH[lg][el][n] = h;
  sA[lg][el][n] = ap;
  __syncthreads();

  // ---- phase 2: prefix combine of group summaries
  if (t < 256){
    float hin = 0.f;
    sHin[0][el][n] = 0.f;
    #pragma unroll
    for (int g=1; g<4; ++g){
      hin = sH[g-1][el][n] + sA[g-1][el][n]*hin;
      sHin[g][el][n] = hin;
    }
  }
  __syncthreads();

  // ---- phase 3: correction walk for groups 1..3 (hin folded into product)
  if (lg > 0){
    float p = sHin[lg][el][n];
    #pragma unroll 4
    for (int l4 = 0; l4 < 16; ++l4){
      f32x4 d4 = *(const f32x4*)&pD[l4*4];
      uint4 bc4 = *(const uint4*)&pBC[l4*4];
      u32 bck[4] = { bc4.x, bc4.y, bc4.z, bc4.w };
      #pragma unroll
      for (int k=0;k<4;k++){
        p *= __expf(d4[k]*Av);
        float Cv = bf2f((u16)(bck[k] >> 16));
        float yc = sum16_dpp(p*Cv);
        if (n==0) sy[lbase + l4*4 + k][el] += yc;
      }
    }
  }
  __syncthreads();

  // ---- gated bf16 store (1024 ushort4)
  {
    float4 y4 = *(const float4*)&sy[sl][se4];
    ushort4 o;
    o.x = f2bf(y4.x * bf2f(gv.x)); o.y = f2bf(y4.y * bf2f(gv.y));
    o.z = f2bf(y4.z * bf2f(gv.z)); o.w = f2bf(y4.w * bf2f(gv.w));
    *(ushort4*)&yp_[(long)sl*DI + e0 + se4] = o;
  }
}

extern "C" void kernel_launch(void* const* d_in, const int* in_sizes, int n_in,
                              void* d_out, int out_size, void* d_ws, size_t ws_size,
                              hipStream_t stream){
  const float* ts   = (const float*)d_in[0];
  const float* ew   = (const float*)d_in[2];
  const float* eb   = (const float*)d_in[3];
  const float* nw   = (const float*)d_in[4];
  const float* inw  = (const float*)d_in[5];
  const float* cw   = (const float*)d_in[6];
  const float* cb   = (const float*)d_in[7];
  const float* xpw  = (const float*)d_in[8];
  const float* dtw  = (const float*)d_in[9];
  const float* dtb  = (const float*)d_in[10];
  const float* alog = (const float*)d_in[11];
  const float* dpp  = (const float*)d_in[12];
  const float* outw = (const float*)d_in[13];
  const float* pw   = (const float*)d_in[14];
  const float* pb   = (const float*)d_in[15];
  float* out = (float*)d_out;

  float* ws   = (float*)d_ws;
  float* x    = ws;                  // 524288
  float* xzu  = ws + 524288;         // 2097152 (u pre-conv, both dirs)
  float* xdbl = ws + 2621440;        // 131072
  float* yout = ws + 2752512;        // 1048576
  float* xpart= ws + 3801088;        // 1048576 (2*8*65536)
  u16* ub     = (u16*)(ws + 4849664);
  u16* xn_bf  = ub;                  // 1048576 (both dirs)
  u16* u_bf   = ub + 1048576;        // 2097152
  u16* g_bf   = ub + 3145728;        // 2097152 (silu(z), both dirs)
  u16* yg_bf  = ub + 5242880;        // 2097152
  u16* x_bf   = ub + 7340032;        // 524288
  u16* wb     = ub + 7864320;        // 26738688 bf16 weights (in|out|xp|pj)
  u16* wb_in  = wb;                  // 16777216
  u16* wb_out = wb + 16777216;       // 8388608
  u16* wb_xp  = wb + 25165824;       // 1048576
  u16* wb_pj  = wb + 26214400;       // 524288

  dim3 blk(256);

  embed_k<<<MT*DM/256, blk, 0, stream>>>(ts, ew, eb, x);
  wcastall_k<<<26112, blk, 0, stream>>>(inw, outw, xpw, pw, wb);

  for (int i=0;i<NLAYER;i++){
    rmscomb_k<<<MT, blk, 0, stream>>>(x, i ? yout : nullptr, nw + i*DM,
        xn_bf, xn_bf + MT*DM);
    // in_proj: (1024x512)@(2048x512)^T; u-half -> xzu fp32, z-half -> silu bf16 g
    mfma_nt<64,128,1,4><<<dim3(16,16,2), blk, 0, stream>>>(
        xn_bf, DM, (long)MT*DM, wb_in + (long)i*2097152, DM, 1048576,
        nullptr, g_bf, xzu, 1024, (long)MT*1024, MT, 2048, DM);
    conv_silu_k<<<2048, blk, 0, stream>>>(xzu, cw + (long)i*2*DI*4, cb + i*2*DI, u_bf);
    // xproj: (1024x1024)@(64x1024)^T split-K=8, 64x64 tiles, 256 blocks
    mfma_nt<64,64,8,0><<<dim3(1,16,16), blk, 0, stream>>>(
        u_bf, DI, (long)MT*DI, wb_xp + (long)i*131072, DI, 65536,
        nullptr, nullptr, xpart, 64, 0, MT, 64, DI);
    xreduce_k<<<512, blk, 0, stream>>>(xpart, xdbl);
    // scan: 1024-thread group-parallel prefix scan, fused fp32 delta-GEMM
    scan_k<<<dim3(64, BS, 2), dim3(1024), 0, stream>>>(u_bf, g_bf, xdbl,
        dtw + (long)i*2*DI*DTR, dtb + (long)i*2*DI,
        alog + (long)i*2*DI*16, dpp + i*2*DI, yg_bf);
    // out_proj: (1024x1024)@(512x1024)^T; 64x64 tiles, 256 blocks
    mfma_nt<64,64,1,0><<<dim3(8,16,2), blk, 0, stream>>>(
        yg_bf, DI, (long)MT*DI, wb_out + (long)i*1048576, DI, 524288,
        nullptr, nullptr, yout, DM, (long)MT*DM, MT, DM, DI);
  }
  combcast_k<<<MT*DM/4/256, blk, 0, stream>>>(x, yout, x_bf);
  // final proj + bias + scatter; 64x64 tiles, 256 blocks
  mfma_nt<64,64,1,2><<<dim3(16,16,1), blk, 0, stream>>>(
      x_bf, DM, 0, wb_pj, DM, 0, pb, nullptr, out, 1024, 0, MT, 1024, DM);
}

// Round 14
// 870.254 us; speedup vs baseline: 1.0282x; 1.0068x over previous
//
#include <hip/hip_runtime.h>
#include <hip/hip_bf16.h>

#define DM 512      // d_model
#define DI 1024     // d_inner
#define DSTATE 16
#define DTR 32      // dt_rank
#define NLAYER 8
#define BS 4
#define LL 256      // tokens per batch (F*NP)
#define MT 1024     // BS*LL total tokens
#define DPROJ 256

typedef unsigned short u16;
typedef unsigned int u32;
typedef __attribute__((ext_vector_type(8))) short short8;
typedef __attribute__((ext_vector_type(4))) float f32x4;

__device__ __forceinline__ float sigmoidf_(float x){ return 1.f/(1.f+__expf(-x)); }

// fp32 -> bf16 round-to-nearest-even (finite inputs)
__device__ __forceinline__ u16 f2bf(float f){
  unsigned u = __float_as_uint(f);
  u = (u + 0x7FFF + ((u>>16)&1)) >> 16;
  return (u16)u;
}
__device__ __forceinline__ float bf2f(u16 v){
  return __uint_as_float(((unsigned)v) << 16);
}

// VALU-pipe 16-lane sum via DPP row rotations
template<int CTRL>
__device__ __forceinline__ float dpp_ror_add(float x){
  int y = __builtin_amdgcn_update_dpp(0, __float_as_int(x), CTRL, 0xF, 0xF, false);
  return x + __int_as_float(y);
}
__device__ __forceinline__ float sum16_dpp(float x){
  x = dpp_ror_add<0x128>(x);
  x = dpp_ror_add<0x124>(x);
  x = dpp_ror_add<0x122>(x);
  x = dpp_ror_add<0x121>(x);
  return x;
}

// ---------------- patch embed
__global__ __launch_bounds__(256) void embed_k(const float* __restrict__ ts,
    const float* __restrict__ ew, const float* __restrict__ eb, float* __restrict__ x){
  int idx = blockIdx.x*256 + threadIdx.x;     // MT*DM
  int m = idx >> 9, d = idx & 511;
  int b = m >> 8, np_ = m & 255;
  const float* t0 = ts + b*1024 + np_*4;
  float acc = eb[d];
  #pragma unroll
  for (int p=0;p<4;p++) acc = fmaf(t0[p], ew[d*4+p], acc);
  x[idx] = acc;
}

// ---------------- cast ALL weights to bf16 once; coalesced float4->ushort4
__global__ __launch_bounds__(256) void wcastall_k(
    const float* __restrict__ w_in, const float* __restrict__ w_out,
    const float* __restrict__ w_xp, const float* __restrict__ w_pj,
    u16* __restrict__ dst){
  int t = blockIdx.x*256 + threadIdx.x;   // 6684672 float4s
  long e4 = (long)t*4;
  const float* src; long o;
  if      (e4 < 16777216) { src = w_in;  o = e4; }
  else if (e4 < 25165824) { src = w_out; o = e4 - 16777216; }
  else if (e4 < 26214400) { src = w_xp;  o = e4 - 25165824; }
  else                    { src = w_pj;  o = e4 - 26214400; }
  float4 v = *(const float4*)(src + o);
  ushort4 r; r.x=f2bf(v.x); r.y=f2bf(v.y); r.z=f2bf(v.z); r.w=f2bf(v.w);
  *(ushort4*)(dst + e4) = r;
}

// ---------------- fused (residual combine) + rmsnorm -> bf16 normal+flipped
__global__ __launch_bounds__(256) void rmscomb_k(float* __restrict__ x,
    const float* __restrict__ yout,   // nullptr for layer 0
    const float* __restrict__ nw, u16* __restrict__ xnbf, u16* __restrict__ xnfbf){
  int m = blockIdx.x, t = threadIdx.x;
  int b = m>>8, l = m&255, mf = (b<<8)+(255-l);
  float2 v = *(const float2*)&x[(long)m*DM + t*2];
  if (yout){
    float2 f = *(const float2*)&yout[(long)m*DM + t*2];
    float2 g = *(const float2*)&yout[(long)MT*DM + (long)mf*DM + t*2];
    v.x += f.x + g.x; v.y += f.y + g.y;
    *(float2*)&x[(long)m*DM + t*2] = v;
  }
  float ss = v.x*v.x + v.y*v.y;
  ss += __shfl_down(ss,32); ss += __shfl_down(ss,16); ss += __shfl_down(ss,8);
  ss += __shfl_down(ss,4);  ss += __shfl_down(ss,2);  ss += __shfl_down(ss,1);
  __shared__ float ps[4];
  if ((t&63)==0) ps[t>>6] = ss;
  __syncthreads();
  float tot = ps[0]+ps[1]+ps[2]+ps[3];
  float rs = rsqrtf(tot*(1.f/DM) + 1e-5f);
  ushort2 o; o.x = f2bf(v.x*rs*nw[t*2]); o.y = f2bf(v.y*rs*nw[t*2+1]);
  *(ushort2*)&xnbf [(long)m *DM + t*2] = o;
  *(ushort2*)&xnfbf[(long)mf*DM + t*2] = o;
}

// ---------------- final combine + cast to bf16
__global__ __launch_bounds__(256) void combcast_k(const float* __restrict__ x,
    const float* __restrict__ yout, u16* __restrict__ xbf){
  int idx = blockIdx.x*256 + threadIdx.x;   // MT*DM/4
  int m = idx >> 7, c4 = idx & 127;
  int b = m>>8, l = m&255, mf = (b<<8)+(255-l);
  float4 r = ((const float4*)x)[idx];
  float4 f = ((const float4*)yout)[idx];
  float4 g = ((const float4*)(yout + (long)MT*DM))[(long)mf*128 + c4];
  ushort4 o;
  o.x = f2bf(r.x + f.x + g.x); o.y = f2bf(r.y + f.y + g.y);
  o.z = f2bf(r.z + f.z + g.z); o.w = f2bf(r.w + f.w + g.w);
  ((ushort4*)xbf)[idx] = o;
}

// ---------------- bf16 MFMA GEMM: C = A @ W^T
// SPLITK>1: z = dir*SPLITK+kc, fp32 partials at C + z*M*N.
// EPI: 0 plain | 2 final scatter+bias | 4 in_proj split: n<1024 -> fp32 C, n>=1024 -> bf16 silu -> G
template<int BM,int BN,int SPLITK,int EPI>
__global__ __launch_bounds__(256) void mfma_nt(
    const u16* __restrict__ A, int lda, long sA,
    const u16* __restrict__ W, int ldw, long sW,
    const float* __restrict__ bias, u16* __restrict__ G,
    float* __restrict__ C, int ldc, long sC,
    int M, int N, int K)
{
  constexpr int WM = BM/2, WN = BN/2;
  constexpr int MI = WM/16, NI = WN/16;
  int z = blockIdx.z;
  int dir = z / SPLITK, kc = z % SPLITK;
  int Klen = K / SPLITK;
  int kbase = kc * Klen;
  A += (long)dir * sA;
  W += (long)dir * sW;
  if (SPLITK > 1) C += (long)z * M * N; else C += (long)dir * sC;
  if (EPI==4) G += (long)dir * (long)MT*DI;

  __shared__ u16 Al[BM*32];
  __shared__ u16 Wl[BN*32];
  int tid = threadIdx.x;
  int lane = tid & 63;
  int wave = tid >> 6;
  int wm0 = (wave>>1)*WM, wn0 = (wave&1)*WN;
  int m0 = blockIdx.y*BM, n0 = blockIdx.x*BN;
  int l16 = lane>>4, l15 = lane&15;

  f32x4 acc[MI][NI] = {};

  for (int k0=0; k0<Klen; k0+=32){
    #pragma unroll
    for (int it=0; it<BM*4/256; ++it){
      int ch = it*256 + tid;
      int row = ch % BM, kk = ch / BM;
      const u16* g = A + (long)(m0+row)*lda + kbase + k0 + kk*8;
      __builtin_amdgcn_global_load_lds(
          (const __attribute__((address_space(1))) void*)g,
          (__attribute__((address_space(3))) void*)(Al + ch*8), 16, 0, 0);
    }
    #pragma unroll
    for (int it=0; it<BN*4/256; ++it){
      int ch = it*256 + tid;
      int row = ch % BN, kk = ch / BN;
      const u16* g = W + (long)(n0+row)*ldw + kbase + k0 + kk*8;
      __builtin_amdgcn_global_load_lds(
          (const __attribute__((address_space(1))) void*)g,
          (__attribute__((address_space(3))) void*)(Wl + ch*8), 16, 0, 0);
    }
    __syncthreads();
    short8 a[MI], b[NI];
    #pragma unroll
    for (int i=0;i<MI;i++)
      a[i] = *(const short8*)&Al[(l16*BM + wm0 + i*16 + l15)*8];
    #pragma unroll
    for (int j=0;j<NI;j++)
      b[j] = *(const short8*)&Wl[(l16*BN + wn0 + j*16 + l15)*8];
    #pragma unroll
    for (int i=0;i<MI;i++)
      #pragma unroll
      for (int j=0;j<NI;j++)
        acc[i][j] = __builtin_amdgcn_mfma_f32_16x16x32_bf16(a[i], b[j], acc[i][j], 0,0,0);
    __syncthreads();
  }
  #pragma unroll
  for (int i=0;i<MI;i++){
    #pragma unroll
    for (int j=0;j<NI;j++){
      #pragma unroll
      for (int r=0;r<4;r++){
        int m = m0 + wm0 + i*16 + l16*4 + r;
        int n = n0 + wn0 + j*16 + l15;
        float v = acc[i][j][r];
        if (EPI==2){
          v += bias[n];
          int bb = m>>8, np_ = m&255, p = n>>8, dp = n&255;
          C[((long)(bb*1024 + np_*4 + p))*256 + dp] = v;
        } else if (EPI==4){
          if (n < 1024) C[(long)m*1024 + n] = v;
          else          G[(long)m*1024 + (n-1024)] = f2bf(v * sigmoidf_(v));
        } else {
          C[(long)m*ldc + n] = v;
        }
      }
    }
  }
}

// ---------------- split-K reduce for xproj
__global__ __launch_bounds__(256) void xreduce_k(const float* __restrict__ part,
    float* __restrict__ xdbl){
  int idx = blockIdx.x*256 + threadIdx.x;   // 131072
  int d = idx >> 16, off = idx & 65535;
  float s = 0.f;
  #pragma unroll
  for (int kc=0; kc<8; ++kc) s += part[((d*8+kc)<<16) + off];
  xdbl[idx] = s;
}

// ---------------- causal depthwise conv + bias + silu -> bf16 u (reads dense xz_u)
__global__ __launch_bounds__(256) void conv_silu_k(const float* __restrict__ xzu,
    const float* __restrict__ cw, const float* __restrict__ cb,
    u16* __restrict__ ubf){
  int idx = blockIdx.x*256 + threadIdx.x;   // 2*MT*DI/4 = 524288
  int e = idx & (DI-1);
  int grp = idx >> 10;          // 512 groups: dir(1) | b(2) | lg(6)
  int dir = grp >> 8;
  int b   = (grp >> 6) & 3;
  int l0  = (grp & 63) * 4;
  long dm0 = (long)dir*MT + b*LL + l0;
  const float* w = cw + ((long)dir*DI + e)*4;
  float w0=w[0], w1=w[1], w2=w[2], w3=w[3];
  float bias = cb[dir*DI + e];
  const float* src = xzu + dm0*DI + e;     // row l0
  float vb[7];
  #pragma unroll
  for (int j=0;j<7;j++){
    int l = l0 - 3 + j;
    vb[j] = (l >= 0) ? src[(long)(j-3)*DI] : 0.f;
  }
  #pragma unroll
  for (int j=0;j<4;j++){
    float acc = bias;
    acc = fmaf(w0, vb[j],   acc);
    acc = fmaf(w1, vb[j+1], acc);
    acc = fmaf(w2, vb[j+2], acc);
    acc = fmaf(w3, vb[j+3], acc);
    float v = acc * sigmoidf_(acc);
    ubf[(dm0+j)*DI + e] = f2bf(v);
  }
}

// ---------------- selective scan: WAVE-SYNCHRONOUS, 64 threads = 1 wave
// thread = (g 0..3 e-group, n 0..15); block owns 4 e's x 256 steps; fused fp32 delta
// grid 2048 blocks (8/CU), no inter-wave barriers
__global__ __launch_bounds__(64) void scan_k(
    const u16* __restrict__ ubf, const u16* __restrict__ gbf,
    const float* __restrict__ xdbl, const float* __restrict__ dtw,
    const float* __restrict__ dtb, const float* __restrict__ A_log,
    const float* __restrict__ Dp, u16* __restrict__ ygbf)
{
  int t = threadIdx.x;
  int n = t & 15, g = t >> 4;                  // g = e-group 0..3
  int id = blockIdx.x + 256*blockIdx.y + 1024*blockIdx.z;   // 0..2047
  int xcd = id & 7, s = id >> 3;
  int ecb = xcd*32 + (s & 31);                 // 0..255
  int rest = s >> 5;                           // 0..7
  int b = rest & 3, dir = rest >> 2;
  int e0 = ecb*4;

  long mbase = (long)dir*MT + b*LL;
  const u16* up_ = ubf + mbase*DI + e0;
  const u16* gp_ = gbf + mbase*DI + e0;
  const float* xd_ = xdbl + mbase*64;
  u16* yp_ = ygbf + mbase*DI + e0;

  // walk-role constants: state (e0+g, n)
  float Av = -__expf(A_log[((long)dir*DI + e0 + g)*16 + n]);
  float Dv = Dp[dir*DI + e0 + g];

  // delta-role: thread (g,n) computes delta(e0+g, l0+n / l0+n+16)
  float wrow[32];
  {
    const float* wr = dtw + ((long)dir*DI + e0 + g)*32;
    #pragma unroll
    for (int r4=0;r4<8;r4++) *(float4*)&wrow[r4*4] = *(const float4*)&wr[r4*4];
  }
  float dtbv = dtb[dir*DI + e0 + g];

  __shared__ u32 sDU[32][4][2];   // [l][g][{0:d fp32 bits, 1:u bf16}]
  __shared__ u32 sBC[32][20];     // [l][n] packed lo=B, hi=C (bf16); 16 used + pad
  __shared__ float sy[32][4];

  // staging regs (chunk c+1 prefetch)
  ushort4 ru, rg;
  float4 rb0, rb1, rc0, rc1;
  int brow = t >> 1, bseg = t & 1;

  auto loadrg = [&](int c){
    int l0 = c*32;
    if (t < 32){
      ru = *(const ushort4*)&up_[(long)(l0 + t)*DI];
      rg = *(const ushort4*)&gp_[(long)(l0 + t)*DI];
    }
    const float* src = &xd_[(long)(l0 + brow)*64 + 32 + bseg*8];
    rb0 = *(const float4*)&src[0];
    rb1 = *(const float4*)&src[4];
    rc0 = *(const float4*)&src[16];
    rc1 = *(const float4*)&src[20];
  };

  loadrg(0);
  float h = 0.f;

  for (int c = 0; c < 8; ++c){
    int l0 = c*32;
    // ---- write staged u and packed BC to LDS
    if (t < 32){
      sDU[t][0][1] = ru.x; sDU[t][1][1] = ru.y;
      sDU[t][2][1] = ru.z; sDU[t][3][1] = ru.w;
    }
    {
      uint4 p0, p1;
      p0.x = (u32)f2bf(rb0.x) | ((u32)f2bf(rc0.x)<<16);
      p0.y = (u32)f2bf(rb0.y) | ((u32)f2bf(rc0.y)<<16);
      p0.z = (u32)f2bf(rb0.z) | ((u32)f2bf(rc0.z)<<16);
      p0.w = (u32)f2bf(rb0.w) | ((u32)f2bf(rc0.w)<<16);
      p1.x = (u32)f2bf(rb1.x) | ((u32)f2bf(rc1.x)<<16);
      p1.y = (u32)f2bf(rb1.y) | ((u32)f2bf(rc1.y)<<16);
      p1.z = (u32)f2bf(rb1.z) | ((u32)f2bf(rc1.z)<<16);
      p1.w = (u32)f2bf(rb1.w) | ((u32)f2bf(rc1.w)<<16);
      *(uint4*)&sBC[brow][bseg*8]     = p0;
      *(uint4*)&sBC[brow][bseg*8 + 4] = p1;
    }
    // ---- fused delta: 2 rows per thread from L2-hot xdbl
    #pragma unroll
    for (int j=0;j<2;j++){
      int l = n + j*16;
      const float* row = &xd_[(long)(l0 + l)*64];
      float acc = dtbv;
      #pragma unroll
      for (int r4=0;r4<8;r4++){
        float4 d4 = *(const float4*)&row[r4*4];
        acc = fmaf(d4.x, wrow[r4*4],   acc);
        acc = fmaf(d4.y, wrow[r4*4+1], acc);
        acc = fmaf(d4.z, wrow[r4*4+2], acc);
        acc = fmaf(d4.w, wrow[r4*4+3], acc);
      }
      acc = fmaxf(acc, 0.f) + __logf(1.f + __expf(-fabsf(acc)));
      sDU[l][g][0] = __float_as_uint(acc);
    }
    ushort4 gcur = rg;                 // gate for this chunk's store
    __syncthreads();                   // single-wave: cheap; orders LDS for compiler
    if (c < 7) loadrg(c+1);            // prefetch next chunk under the walk

    // ---- serial walk, 32 steps
    #pragma unroll 8
    for (int l = 0; l < 32; ++l){
      uint2 du = *(const uint2*)&sDU[l][g][0];
      float dv = __uint_as_float(du.x);
      float uv = bf2f((u16)du.y);
      u32 bc = sBC[l][n];
      float Bv = bf2f((u16)(bc & 0xffff));
      float Cv = bf2f((u16)(bc >> 16));
      float dA = __expf(dv*Av);
      h = fmaf(dA, h, dv*uv*Bv);
      float yc = sum16_dpp(h*Cv);
      if (n==0) sy[l][g] = yc + uv*Dv;
    }
    __builtin_amdgcn_wave_barrier();   // keep sy writes before reads

    // ---- gated bf16 store for this chunk
    if (t < 32){
      float4 y4 = *(const float4*)&sy[t][0];
      ushort4 o;
      o.x = f2bf(y4.x * bf2f(gcur.x)); o.y = f2bf(y4.y * bf2f(gcur.y));
      o.z = f2bf(y4.z * bf2f(gcur.z)); o.w = f2bf(y4.w * bf2f(gcur.w));
      *(ushort4*)&yp_[(long)(l0 + t)*DI] = o;
    }
    __syncthreads();
  }
}

extern "C" void kernel_launch(void* const* d_in, const int* in_sizes, int n_in,
                              void* d_out, int out_size, void* d_ws, size_t ws_size,
                              hipStream_t stream){
  const float* ts   = (const float*)d_in[0];
  const float* ew   = (const float*)d_in[2];
  const float* eb   = (const float*)d_in[3];
  const float* nw   = (const float*)d_in[4];
  const float* inw  = (const float*)d_in[5];
  const float* cw   = (const float*)d_in[6];
  const float* cb   = (const float*)d_in[7];
  const float* xpw  = (const float*)d_in[8];
  const float* dtw  = (const float*)d_in[9];
  const float* dtb  = (const float*)d_in[10];
  const float* alog = (const float*)d_in[11];
  const float* dpp  = (const float*)d_in[12];
  const float* outw = (const float*)d_in[13];
  const float* pw   = (const float*)d_in[14];
  const float* pb   = (const float*)d_in[15];
  float* out = (float*)d_out;

  float* ws   = (float*)d_ws;
  float* x    = ws;                  // 524288
  float* xzu  = ws + 524288;         // 2097152 (u pre-conv, both dirs)
  float* xdbl = ws + 2621440;        // 131072
  float* yout = ws + 2752512;        // 1048576
  float* xpart= ws + 3801088;        // 1048576 (2*8*65536)
  u16* ub     = (u16*)(ws + 4849664);
  u16* xn_bf  = ub;                  // 1048576 (both dirs)
  u16* u_bf   = ub + 1048576;        // 2097152
  u16* g_bf   = ub + 3145728;        // 2097152 (silu(z), both dirs)
  u16* yg_bf  = ub + 5242880;        // 2097152
  u16* x_bf   = ub + 7340032;        // 524288
  u16* wb     = ub + 7864320;        // 26738688 bf16 weights (in|out|xp|pj)
  u16* wb_in  = wb;                  // 16777216
  u16* wb_out = wb + 16777216;       // 8388608
  u16* wb_xp  = wb + 25165824;       // 1048576
  u16* wb_pj  = wb + 26214400;       // 524288

  dim3 blk(256);

  embed_k<<<MT*DM/256, blk, 0, stream>>>(ts, ew, eb, x);
  wcastall_k<<<26112, blk, 0, stream>>>(inw, outw, xpw, pw, wb);

  for (int i=0;i<NLAYER;i++){
    rmscomb_k<<<MT, blk, 0, stream>>>(x, i ? yout : nullptr, nw + i*DM,
        xn_bf, xn_bf + MT*DM);
    // in_proj: (1024x512)@(2048x512)^T; u-half -> xzu fp32, z-half -> silu bf16 g
    mfma_nt<64,128,1,4><<<dim3(16,16,2), blk, 0, stream>>>(
        xn_bf, DM, (long)MT*DM, wb_in + (long)i*2097152, DM, 1048576,
        nullptr, g_bf, xzu, 1024, (long)MT*1024, MT, 2048, DM);
    conv_silu_k<<<2048, blk, 0, stream>>>(xzu, cw + (long)i*2*DI*4, cb + i*2*DI, u_bf);
    // xproj: (1024x1024)@(64x1024)^T split-K=8, 64x64 tiles, 256 blocks
    mfma_nt<64,64,8,0><<<dim3(1,16,16), blk, 0, stream>>>(
        u_bf, DI, (long)MT*DI, wb_xp + (long)i*131072, DI, 65536,
        nullptr, nullptr, xpart, 64, 0, MT, 64, DI);
    xreduce_k<<<512, blk, 0, stream>>>(xpart, xdbl);
    // scan: wave-synchronous 64-thread blocks, fused fp32 delta-GEMM
    scan_k<<<dim3(256, BS, 2), dim3(64), 0, stream>>>(u_bf, g_bf, xdbl,
        dtw + (long)i*2*DI*DTR, dtb + (long)i*2*DI,
        alog + (long)i*2*DI*16, dpp + i*2*DI, yg_bf);
    // out_proj: (1024x1024)@(512x1024)^T; 64x64 tiles, 256 blocks
    mfma_nt<64,64,1,0><<<dim3(8,16,2), blk, 0, stream>>>(
        yg_bf, DI, (long)MT*DI, wb_out + (long)i*1048576, DI, 524288,
        nullptr, nullptr, yout, DM, (long)MT*DM, MT, DM, DI);
  }
  combcast_k<<<MT*DM/4/256, blk, 0, stream>>>(x, yout, x_bf);
  // final proj + bias + scatter; 64x64 tiles, 256 blocks
  mfma_nt<64,64,1,2><<<dim3(16,16,1), blk, 0, stream>>>(
      x_bf, DM, 0, wb_pj, DM, 0, pb, nullptr, out, 1024, 0, MT, 1024, DM);
}

// Round 15
// 824.631 us; speedup vs baseline: 1.0851x; 1.0553x over previous
//
#include <hip/hip_runtime.h>
#include <hip/hip_bf16.h>

#define DM 512      // d_model
#define DI 1024     // d_inner
#define DSTATE 16
#define DTR 32      // dt_rank
#define NLAYER 8
#define BS 4
#define LL 256      // tokens per batch (F*NP)
#define MT 1024     // BS*LL total tokens
#define DPROJ 256

typedef unsigned short u16;
typedef unsigned int u32;
typedef __attribute__((ext_vector_type(8))) short short8;
typedef __attribute__((ext_vector_type(4))) float f32x4;

__device__ __forceinline__ float sigmoidf_(float x){ return 1.f/(1.f+__expf(-x)); }

// fp32 -> bf16 round-to-nearest-even (finite inputs)
__device__ __forceinline__ u16 f2bf(float f){
  unsigned u = __float_as_uint(f);
  u = (u + 0x7FFF + ((u>>16)&1)) >> 16;
  return (u16)u;
}
__device__ __forceinline__ float bf2f(u16 v){
  return __uint_as_float(((unsigned)v) << 16);
}

// VALU-pipe 16-lane sum via DPP row rotations
template<int CTRL>
__device__ __forceinline__ float dpp_ror_add(float x){
  int y = __builtin_amdgcn_update_dpp(0, __float_as_int(x), CTRL, 0xF, 0xF, false);
  return x + __int_as_float(y);
}
__device__ __forceinline__ float sum16_dpp(float x){
  x = dpp_ror_add<0x128>(x);
  x = dpp_ror_add<0x124>(x);
  x = dpp_ror_add<0x122>(x);
  x = dpp_ror_add<0x121>(x);
  return x;
}

// ---------------- patch embed
__global__ __launch_bounds__(256) void embed_k(const float* __restrict__ ts,
    const float* __restrict__ ew, const float* __restrict__ eb, float* __restrict__ x){
  int idx = blockIdx.x*256 + threadIdx.x;     // MT*DM
  int m = idx >> 9, d = idx & 511;
  int b = m >> 8, np_ = m & 255;
  const float* t0 = ts + b*1024 + np_*4;
  float acc = eb[d];
  #pragma unroll
  for (int p=0;p<4;p++) acc = fmaf(t0[p], ew[d*4+p], acc);
  x[idx] = acc;
}

// ---------------- cast ALL weights to bf16 once; coalesced float4->ushort4
__global__ __launch_bounds__(256) void wcastall_k(
    const float* __restrict__ w_in, const float* __restrict__ w_out,
    const float* __restrict__ w_xp, const float* __restrict__ w_pj,
    u16* __restrict__ dst){
  int t = blockIdx.x*256 + threadIdx.x;   // 6684672 float4s
  long e4 = (long)t*4;
  const float* src; long o;
  if      (e4 < 16777216) { src = w_in;  o = e4; }
  else if (e4 < 25165824) { src = w_out; o = e4 - 16777216; }
  else if (e4 < 26214400) { src = w_xp;  o = e4 - 25165824; }
  else                    { src = w_pj;  o = e4 - 26214400; }
  float4 v = *(const float4*)(src + o);
  ushort4 r; r.x=f2bf(v.x); r.y=f2bf(v.y); r.z=f2bf(v.z); r.w=f2bf(v.w);
  *(ushort4*)(dst + e4) = r;
}

// ---------------- fused (residual combine) + rmsnorm -> bf16 normal+flipped
__global__ __launch_bounds__(256) void rmscomb_k(float* __restrict__ x,
    const float* __restrict__ yout,   // nullptr for layer 0
    const float* __restrict__ nw, u16* __restrict__ xnbf, u16* __restrict__ xnfbf){
  int m = blockIdx.x, t = threadIdx.x;
  int b = m>>8, l = m&255, mf = (b<<8)+(255-l);
  float2 v = *(const float2*)&x[(long)m*DM + t*2];
  if (yout){
    float2 f = *(const float2*)&yout[(long)m*DM + t*2];
    float2 g = *(const float2*)&yout[(long)MT*DM + (long)mf*DM + t*2];
    v.x += f.x + g.x; v.y += f.y + g.y;
    *(float2*)&x[(long)m*DM + t*2] = v;
  }
  float ss = v.x*v.x + v.y*v.y;
  ss += __shfl_down(ss,32); ss += __shfl_down(ss,16); ss += __shfl_down(ss,8);
  ss += __shfl_down(ss,4);  ss += __shfl_down(ss,2);  ss += __shfl_down(ss,1);
  __shared__ float ps[4];
  if ((t&63)==0) ps[t>>6] = ss;
  __syncthreads();
  float tot = ps[0]+ps[1]+ps[2]+ps[3];
  float rs = rsqrtf(tot*(1.f/DM) + 1e-5f);
  ushort2 o; o.x = f2bf(v.x*rs*nw[t*2]); o.y = f2bf(v.y*rs*nw[t*2+1]);
  *(ushort2*)&xnbf [(long)m *DM + t*2] = o;
  *(ushort2*)&xnfbf[(long)mf*DM + t*2] = o;
}

// ---------------- final combine + cast to bf16
__global__ __launch_bounds__(256) void combcast_k(const float* __restrict__ x,
    const float* __restrict__ yout, u16* __restrict__ xbf){
  int idx = blockIdx.x*256 + threadIdx.x;   // MT*DM/4
  int m = idx >> 7, c4 = idx & 127;
  int b = m>>8, l = m&255, mf = (b<<8)+(255-l);
  float4 r = ((const float4*)x)[idx];
  float4 f = ((const float4*)yout)[idx];
  float4 g = ((const float4*)(yout + (long)MT*DM))[(long)mf*128 + c4];
  ushort4 o;
  o.x = f2bf(r.x + f.x + g.x); o.y = f2bf(r.y + f.y + g.y);
  o.z = f2bf(r.z + f.z + g.z); o.w = f2bf(r.w + f.w + g.w);
  ((ushort4*)xbf)[idx] = o;
}

// ---------------- bf16 MFMA GEMM: C = A @ W^T
// SPLITK>1: z = dir*SPLITK+kc, fp32 partials at C + z*M*N.
// EPI: 0 plain | 2 final scatter+bias | 4 in_proj split: n<1024 -> fp32 C, n>=1024 -> bf16 silu -> G
template<int BM,int BN,int SPLITK,int EPI>
__global__ __launch_bounds__(256) void mfma_nt(
    const u16* __restrict__ A, int lda, long sA,
    const u16* __restrict__ W, int ldw, long sW,
    const float* __restrict__ bias, u16* __restrict__ G,
    float* __restrict__ C, int ldc, long sC,
    int M, int N, int K)
{
  constexpr int WM = BM/2, WN = BN/2;
  constexpr int MI = WM/16, NI = WN/16;
  int z = blockIdx.z;
  int dir = z / SPLITK, kc = z % SPLITK;
  int Klen = K / SPLITK;
  int kbase = kc * Klen;
  A += (long)dir * sA;
  W += (long)dir * sW;
  if (SPLITK > 1) C += (long)z * M * N; else C += (long)dir * sC;
  if (EPI==4) G += (long)dir * (long)MT*DI;

  __shared__ u16 Al[BM*32];
  __shared__ u16 Wl[BN*32];
  int tid = threadIdx.x;
  int lane = tid & 63;
  int wave = tid >> 6;
  int wm0 = (wave>>1)*WM, wn0 = (wave&1)*WN;
  int m0 = blockIdx.y*BM, n0 = blockIdx.x*BN;
  int l16 = lane>>4, l15 = lane&15;

  f32x4 acc[MI][NI] = {};

  for (int k0=0; k0<Klen; k0+=32){
    #pragma unroll
    for (int it=0; it<BM*4/256; ++it){
      int ch = it*256 + tid;
      int row = ch % BM, kk = ch / BM;
      const u16* g = A + (long)(m0+row)*lda + kbase + k0 + kk*8;
      __builtin_amdgcn_global_load_lds(
          (const __attribute__((address_space(1))) void*)g,
          (__attribute__((address_space(3))) void*)(Al + ch*8), 16, 0, 0);
    }
    #pragma unroll
    for (int it=0; it<BN*4/256; ++it){
      int ch = it*256 + tid;
      int row = ch % BN, kk = ch / BN;
      const u16* g = W + (long)(n0+row)*ldw + kbase + k0 + kk*8;
      __builtin_amdgcn_global_load_lds(
          (const __attribute__((address_space(1))) void*)g,
          (__attribute__((address_space(3))) void*)(Wl + ch*8), 16, 0, 0);
    }
    __syncthreads();
    short8 a[MI], b[NI];
    #pragma unroll
    for (int i=0;i<MI;i++)
      a[i] = *(const short8*)&Al[(l16*BM + wm0 + i*16 + l15)*8];
    #pragma unroll
    for (int j=0;j<NI;j++)
      b[j] = *(const short8*)&Wl[(l16*BN + wn0 + j*16 + l15)*8];
    #pragma unroll
    for (int i=0;i<MI;i++)
      #pragma unroll
      for (int j=0;j<NI;j++)
        acc[i][j] = __builtin_amdgcn_mfma_f32_16x16x32_bf16(a[i], b[j], acc[i][j], 0,0,0);
    __syncthreads();
  }
  #pragma unroll
  for (int i=0;i<MI;i++){
    #pragma unroll
    for (int j=0;j<NI;j++){
      #pragma unroll
      for (int r=0;r<4;r++){
        int m = m0 + wm0 + i*16 + l16*4 + r;
        int n = n0 + wn0 + j*16 + l15;
        float v = acc[i][j][r];
        if (EPI==2){
          v += bias[n];
          int bb = m>>8, np_ = m&255, p = n>>8, dp = n&255;
          C[((long)(bb*1024 + np_*4 + p))*256 + dp] = v;
        } else if (EPI==4){
          if (n < 1024) C[(long)m*1024 + n] = v;
          else          G[(long)m*1024 + (n-1024)] = f2bf(v * sigmoidf_(v));
        } else {
          C[(long)m*ldc + n] = v;
        }
      }
    }
  }
}

// ---------------- split-K reduce for xproj
__global__ __launch_bounds__(256) void xreduce_k(const float* __restrict__ part,
    float* __restrict__ xdbl){
  int idx = blockIdx.x*256 + threadIdx.x;   // 131072
  int d = idx >> 16, off = idx & 65535;
  float s = 0.f;
  #pragma unroll
  for (int kc=0; kc<8; ++kc) s += part[((d*8+kc)<<16) + off];
  xdbl[idx] = s;
}

// ---------------- causal depthwise conv + bias + silu -> bf16 u (reads dense xz_u)
__global__ __launch_bounds__(256) void conv_silu_k(const float* __restrict__ xzu,
    const float* __restrict__ cw, const float* __restrict__ cb,
    u16* __restrict__ ubf){
  int idx = blockIdx.x*256 + threadIdx.x;   // 2*MT*DI/4 = 524288
  int e = idx & (DI-1);
  int grp = idx >> 10;          // 512 groups: dir(1) | b(2) | lg(6)
  int dir = grp >> 8;
  int b   = (grp >> 6) & 3;
  int l0  = (grp & 63) * 4;
  long dm0 = (long)dir*MT + b*LL + l0;
  const float* w = cw + ((long)dir*DI + e)*4;
  float w0=w[0], w1=w[1], w2=w[2], w3=w[3];
  float bias = cb[dir*DI + e];
  const float* src = xzu + dm0*DI + e;     // row l0
  float vb[7];
  #pragma unroll
  for (int j=0;j<7;j++){
    int l = l0 - 3 + j;
    vb[j] = (l >= 0) ? src[(long)(j-3)*DI] : 0.f;
  }
  #pragma unroll
  for (int j=0;j<4;j++){
    float acc = bias;
    acc = fmaf(w0, vb[j],   acc);
    acc = fmaf(w1, vb[j+1], acc);
    acc = fmaf(w2, vb[j+2], acc);
    acc = fmaf(w3, vb[j+3], acc);
    float v = acc * sigmoidf_(acc);
    ubf[(dm0+j)*DI + e] = f2bf(v);
  }
}

// ---------------- selective scan: wave-synchronous, batched chain
// thread = (g 0..3 e-group, n 0..15); 64-thr blocks, grid 2048
// per 32-step chunk: batch-precompute dA/sv/bc/ud in regs -> serial chain is 32 fma only
__global__ __launch_bounds__(64) void scan_k(
    const u16* __restrict__ ubf, const u16* __restrict__ gbf,
    const float* __restrict__ xdbl, const float* __restrict__ dtw,
    const float* __restrict__ dtb, const float* __restrict__ A_log,
    const float* __restrict__ Dp, u16* __restrict__ ygbf)
{
  int t = threadIdx.x;
  int n = t & 15, g = t >> 4;                  // g = e-group 0..3
  int id = blockIdx.x + 256*blockIdx.y + 1024*blockIdx.z;   // 0..2047
  int xcd = id & 7, s = id >> 3;
  int ecb = xcd*32 + (s & 31);                 // 0..255
  int rest = s >> 5;                           // 0..7
  int b = rest & 3, dir = rest >> 2;
  int e0 = ecb*4;

  long mbase = (long)dir*MT + b*LL;
  const u16* up_ = ubf + mbase*DI + e0;
  const u16* gp_ = gbf + mbase*DI + e0;
  const float* xd_ = xdbl + mbase*64;
  u16* yp_ = ygbf + mbase*DI + e0;

  // walk-role constants: state (e0+g, n)
  float Av = -__expf(A_log[((long)dir*DI + e0 + g)*16 + n]);
  float Dv = Dp[dir*DI + e0 + g];

  // delta-role: thread (g,n) computes delta(e0+g, l0+n / l0+n+16)
  float wrow[32];
  {
    const float* wr = dtw + ((long)dir*DI + e0 + g)*32;
    #pragma unroll
    for (int r4=0;r4<8;r4++) *(float4*)&wrow[r4*4] = *(const float4*)&wr[r4*4];
  }
  float dtbv = dtb[dir*DI + e0 + g];

  __shared__ u32 sDU[4][80];      // [g][2*l + {0:d fp32 bits, 1:u bf16}] (64 used + pad)
  __shared__ u32 sBC[16][36];     // [n][l] packed lo=B, hi=C (bf16); 32 used + pad
  __shared__ float sy[32][4];

  // staging regs (chunk prefetch)
  ushort4 ru, rg;
  float4 rb0, rb1, rc0, rc1;
  int brow = t >> 1, bseg = t & 1;

  auto loadrg = [&](int c){
    int l0 = c*32;
    if (t < 32){
      ru = *(const ushort4*)&up_[(long)(l0 + t)*DI];
      rg = *(const ushort4*)&gp_[(long)(l0 + t)*DI];
    }
    const float* src = &xd_[(long)(l0 + brow)*64 + 32 + bseg*8];
    rb0 = *(const float4*)&src[0];
    rb1 = *(const float4*)&src[4];
    rc0 = *(const float4*)&src[16];
    rc1 = *(const float4*)&src[20];
  };

  loadrg(0);
  float h = 0.f;

  for (int c = 0; c < 8; ++c){
    int l0 = c*32;
    // ---- write staged u (t<32 holds row l=t, 4 e's)
    if (t < 32){
      sDU[0][2*t+1] = ru.x; sDU[1][2*t+1] = ru.y;
      sDU[2][2*t+1] = ru.z; sDU[3][2*t+1] = ru.w;
    }
    // ---- write packed BC transposed to [n][l]
    {
      u32 pb[8];
      pb[0] = (u32)f2bf(rb0.x) | ((u32)f2bf(rc0.x)<<16);
      pb[1] = (u32)f2bf(rb0.y) | ((u32)f2bf(rc0.y)<<16);
      pb[2] = (u32)f2bf(rb0.z) | ((u32)f2bf(rc0.z)<<16);
      pb[3] = (u32)f2bf(rb0.w) | ((u32)f2bf(rc0.w)<<16);
      pb[4] = (u32)f2bf(rb1.x) | ((u32)f2bf(rc1.x)<<16);
      pb[5] = (u32)f2bf(rb1.y) | ((u32)f2bf(rc1.y)<<16);
      pb[6] = (u32)f2bf(rb1.z) | ((u32)f2bf(rc1.z)<<16);
      pb[7] = (u32)f2bf(rb1.w) | ((u32)f2bf(rc1.w)<<16);
      #pragma unroll
      for (int k=0;k<8;k++) sBC[bseg*8 + k][brow] = pb[k];
    }
    // ---- fused delta: 2 rows per thread from L2-hot xdbl
    #pragma unroll
    for (int j=0;j<2;j++){
      int l = n + j*16;
      const float* row = &xd_[(long)(l0 + l)*64];
      float acc = dtbv;
      #pragma unroll
      for (int r4=0;r4<8;r4++){
        float4 d4 = *(const float4*)&row[r4*4];
        acc = fmaf(d4.x, wrow[r4*4],   acc);
        acc = fmaf(d4.y, wrow[r4*4+1], acc);
        acc = fmaf(d4.z, wrow[r4*4+2], acc);
        acc = fmaf(d4.w, wrow[r4*4+3], acc);
      }
      acc = fmaxf(acc, 0.f) + __logf(1.f + __expf(-fabsf(acc)));
      sDU[g][2*l] = __float_as_uint(acc);
    }
    ushort4 gcur = rg;                 // gate for this chunk's store
    __syncthreads();
    if (c < 7) loadrg(c+1);            // prefetch next chunk under compute

    // ---- batch-load walk inputs to registers (broadcast/2-way LDS reads)
    float dA[32], sv[32], ud[32];
    u32  bcp[32];
    {
      const u32* pdu = &sDU[g][0];
      const u32* pbc = &sBC[n][0];
      #pragma unroll
      for (int l4=0; l4<8; ++l4){
        uint4 a0 = *(const uint4*)&pdu[l4*8];      // l = 4*l4+0,1 : {d,u}x2
        uint4 a1 = *(const uint4*)&pdu[l4*8+4];    // l = 4*l4+2,3
        uint4 bc = *(const uint4*)&pbc[l4*4];
        int L = l4*4;
        float dv0 = __uint_as_float(a0.x), uv0 = bf2f((u16)a0.y);
        float dv1 = __uint_as_float(a0.z), uv1 = bf2f((u16)a0.w);
        float dv2 = __uint_as_float(a1.x), uv2 = bf2f((u16)a1.y);
        float dv3 = __uint_as_float(a1.z), uv3 = bf2f((u16)a1.w);
        dA[L  ] = __expf(dv0*Av); sv[L  ] = dv0*uv0*bf2f((u16)(bc.x & 0xffff)); ud[L  ] = uv0*Dv;
        dA[L+1] = __expf(dv1*Av); sv[L+1] = dv1*uv1*bf2f((u16)(bc.y & 0xffff)); ud[L+1] = uv1*Dv;
        dA[L+2] = __expf(dv2*Av); sv[L+2] = dv2*uv2*bf2f((u16)(bc.z & 0xffff)); ud[L+2] = uv2*Dv;
        dA[L+3] = __expf(dv3*Av); sv[L+3] = dv3*uv3*bf2f((u16)(bc.w & 0xffff)); ud[L+3] = uv3*Dv;
        bcp[L] = bc.x; bcp[L+1] = bc.y; bcp[L+2] = bc.z; bcp[L+3] = bc.w;
      }
    }
    // ---- serial chain: 32 dependent fma only
    #pragma unroll
    for (int l=0; l<32; ++l){
      h = fmaf(dA[l], h, sv[l]);
      sv[l] = h;                       // reuse sv as h-history
    }
    // ---- multiply by C and batched butterfly reduce (independent chains)
    #pragma unroll
    for (int l=0; l<32; ++l) sv[l] *= bf2f((u16)(bcp[l] >> 16));
    #pragma unroll
    for (int l=0; l<32; ++l) sv[l] = sum16_dpp(sv[l]);
    // ---- y = sum + u*D on n==0 lanes; static-indexed stores
    if (n == 0){
      #pragma unroll
      for (int l=0; l<32; ++l) sy[l][g] = sv[l] + ud[l];
    }
    __builtin_amdgcn_wave_barrier();

    // ---- gated bf16 store for this chunk
    if (t < 32){
      float4 y4 = *(const float4*)&sy[t][0];
      ushort4 o;
      o.x = f2bf(y4.x * bf2f(gcur.x)); o.y = f2bf(y4.y * bf2f(gcur.y));
      o.z = f2bf(y4.z * bf2f(gcur.z)); o.w = f2bf(y4.w * bf2f(gcur.w));
      *(ushort4*)&yp_[(long)(l0 + t)*DI] = o;
    }
    __syncthreads();
  }
}

extern "C" void kernel_launch(void* const* d_in, const int* in_sizes, int n_in,
                              void* d_out, int out_size, void* d_ws, size_t ws_size,
                              hipStream_t stream){
  const float* ts   = (const float*)d_in[0];
  const float* ew   = (const float*)d_in[2];
  const float* eb   = (const float*)d_in[3];
  const float* nw   = (const float*)d_in[4];
  const float* inw  = (const float*)d_in[5];
  const float* cw   = (const float*)d_in[6];
  const float* cb   = (const float*)d_in[7];
  const float* xpw  = (const float*)d_in[8];
  const float* dtw  = (const float*)d_in[9];
  const float* dtb  = (const float*)d_in[10];
  const float* alog = (const float*)d_in[11];
  const float* dpp  = (const float*)d_in[12];
  const float* outw = (const float*)d_in[13];
  const float* pw   = (const float*)d_in[14];
  const float* pb   = (const float*)d_in[15];
  float* out = (float*)d_out;

  float* ws   = (float*)d_ws;
  float* x    = ws;                  // 524288
  float* xzu  = ws + 524288;         // 2097152 (u pre-conv, both dirs)
  float* xdbl = ws + 2621440;        // 131072
  float* yout = ws + 2752512;        // 1048576
  float* xpart= ws + 3801088;        // 1048576 (2*8*65536)
  u16* ub     = (u16*)(ws + 4849664);
  u16* xn_bf  = ub;                  // 1048576 (both dirs)
  u16* u_bf   = ub + 1048576;        // 2097152
  u16* g_bf   = ub + 3145728;        // 2097152 (silu(z), both dirs)
  u16* yg_bf  = ub + 5242880;        // 2097152
  u16* x_bf   = ub + 7340032;        // 524288
  u16* wb     = ub + 7864320;        // 26738688 bf16 weights (in|out|xp|pj)
  u16* wb_in  = wb;                  // 16777216
  u16* wb_out = wb + 16777216;       // 8388608
  u16* wb_xp  = wb + 25165824;       // 1048576
  u16* wb_pj  = wb + 26214400;       // 524288

  dim3 blk(256);

  embed_k<<<MT*DM/256, blk, 0, stream>>>(ts, ew, eb, x);
  wcastall_k<<<26112, blk, 0, stream>>>(inw, outw, xpw, pw, wb);

  for (int i=0;i<NLAYER;i++){
    rmscomb_k<<<MT, blk, 0, stream>>>(x, i ? yout : nullptr, nw + i*DM,
        xn_bf, xn_bf + MT*DM);
    // in_proj: (1024x512)@(2048x512)^T; u-half -> xzu fp32, z-half -> silu bf16 g
    mfma_nt<64,128,1,4><<<dim3(16,16,2), blk, 0, stream>>>(
        xn_bf, DM, (long)MT*DM, wb_in + (long)i*2097152, DM, 1048576,
        nullptr, g_bf, xzu, 1024, (long)MT*1024, MT, 2048, DM);
    conv_silu_k<<<2048, blk, 0, stream>>>(xzu, cw + (long)i*2*DI*4, cb + i*2*DI, u_bf);
    // xproj: (1024x1024)@(64x1024)^T split-K=8, 64x64 tiles, 256 blocks
    mfma_nt<64,64,8,0><<<dim3(1,16,16), blk, 0, stream>>>(
        u_bf, DI, (long)MT*DI, wb_xp + (long)i*131072, DI, 65536,
        nullptr, nullptr, xpart, 64, 0, MT, 64, DI);
    xreduce_k<<<512, blk, 0, stream>>>(xpart, xdbl);
    // scan: wave-synchronous, batched-chain
    scan_k<<<dim3(256, BS, 2), dim3(64), 0, stream>>>(u_bf, g_bf, xdbl,
        dtw + (long)i*2*DI*DTR, dtb + (long)i*2*DI,
        alog + (long)i*2*DI*16, dpp + i*2*DI, yg_bf);
    // out_proj: (1024x1024)@(512x1024)^T; 64x64 tiles, 256 blocks
    mfma_nt<64,64,1,0><<<dim3(8,16,2), blk, 0, stream>>>(
        yg_bf, DI, (long)MT*DI, wb_out + (long)i*1048576, DI, 524288,
        nullptr, nullptr, yout, DM, (long)MT*DM, MT, DM, DI);
  }
  combcast_k<<<MT*DM/4/256, blk, 0, stream>>>(x, yout, x_bf);
  // final proj + bias + scatter; 64x64 tiles, 256 blocks
  mfma_nt<64,64,1,2><<<dim3(16,16,1), blk, 0, stream>>>(
      x_bf, DM, 0, wb_pj, DM, 0, pb, nullptr, out, 1024, 0, MT, 1024, DM);
}